// Round 5
// baseline (524.788 us; speedup 1.0000x reference)
//
#include <hip/hip_runtime.h>
#include <hip/hip_bf16.h>

// Output: (1, 8, 4096, 4096) float32, 512 MiB per call -> write-BW bound.
//   c in [0,4):  out[c,i,j] = table[seq[i]*4 + c]      (constant along j)
//   c in [4,8):  out[c,i,j] = table[seq[j]*4 + (c-4)]  (depends on j only)
//
// R5: mimic __amd_rocclr_fillBufferAligned's structure exactly (it sustains
// 6.25 TB/s on this device in the same capture): 2048 blocks x 256 threads,
// grid-stride loop, 64 plain dwordx4 stores per thread. Purpose: final
// discriminator between "kernel already at fill ceiling (~86us)" vs
// "kernel stuck at ~3 TB/s (~172us)".

#define L 4096
#define NTHREADS (2048u * 256u)          // 524288 threads
#define TOTAL_F4 (8u * L * L / 4u)       // 33,554,432 float4s
#define NITER (TOTAL_F4 / NTHREADS)      // 64 stores/thread

typedef float v4f __attribute__((ext_vector_type(4)));
typedef int   v4i __attribute__((ext_vector_type(4)));

__global__ __launch_bounds__(256) void SequenceEmbedding_30923764532139_kernel(
        const int* __restrict__ seq,
        const float* __restrict__ table,
        v4f* __restrict__ out) {
    unsigned tid = blockIdx.x * blockDim.x + threadIdx.x;

    // Preload the whole 4x4 table (seq values are 0..3).
    float tab[16];
    #pragma unroll
    for (int q = 0; q < 4; ++q) {
        v4f r = *(const v4f*)(table + 4 * q);
        tab[4 * q + 0] = r.x; tab[4 * q + 1] = r.y;
        tab[4 * q + 2] = r.z; tab[4 * q + 3] = r.w;
    }

    #pragma unroll
    for (unsigned k = 0; k < NITER; ++k) {
        unsigned idx = tid + k * NTHREADS;          // float4 index, exact cover
        unsigned c   = idx >> 22;                   // plane 0..7 (wave-uniform)
        unsigned i   = (idx >> 10) & (L - 1);       // row (wave-uniform)
        unsigned jf4 = idx & 1023u;                 // float4 within row
        unsigned cc  = c & 3u;                      // table column

        v4f val;
        if (c < 4u) {
            float x = tab[4u * (unsigned)seq[i] + cc];   // wave-broadcast load
            val = (v4f){x, x, x, x};
        } else {
            v4i s = *(const v4i*)(seq + 4u * jf4);       // coalesced 16B load (L1/L2 hit)
            val.x = tab[4u * (unsigned)s.x + cc];
            val.y = tab[4u * (unsigned)s.y + cc];
            val.z = tab[4u * (unsigned)s.z + cc];
            val.w = tab[4u * (unsigned)s.w + cc];
        }
        out[idx] = val;                                  // plain global_store_dwordx4
    }
}

extern "C" void kernel_launch(void* const* d_in, const int* in_sizes, int n_in,
                              void* d_out, int out_size, void* d_ws, size_t ws_size,
                              hipStream_t stream) {
    const int*   seq   = (const int*)d_in[0];
    const float* table = (const float*)d_in[1];
    v4f*         out   = (v4f*)d_out;

    SequenceEmbedding_30923764532139_kernel<<<dim3(2048), dim3(256), 0, stream>>>(
        seq, table, out);
}